// Round 2
// baseline (299.606 us; speedup 1.0000x reference)
//
#include <hip/hip_runtime.h>
#include <stdint.h>

#define PTS 256                 // threads per block
#define PPT 2                   // points per thread -> 80 B = 5 x float4, 16-B aligned
#define DIM 10

// Codebook as compile-time constant. Fully unrolled uses constant-fold:
// dot loop -> add/sub chain, mask table -> inline cndmask constants.
static constexpr float CB[32][10] = {
 {-1,-1,-1,-1,-1,-1,-1,-1,-1,-1},{-1,-1,-1,-1,1,1,-1,-1,-1,1},{-1,-1,-1,1,-1,-1,-1,-1,1,1},{-1,-1,-1,1,1,1,-1,-1,1,-1},
 {-1,-1,1,-1,-1,-1,-1,1,1,-1},{-1,-1,1,-1,1,1,-1,1,1,1},{-1,-1,1,1,-1,-1,-1,1,-1,1},{-1,-1,1,1,1,1,-1,1,-1,-1},
 {-1,1,-1,-1,-1,-1,1,1,-1,-1},{-1,1,-1,-1,1,1,1,1,-1,1},{-1,1,-1,1,-1,-1,1,1,1,1},{-1,1,-1,1,1,1,1,1,1,-1},
 {-1,1,1,-1,-1,-1,1,-1,1,-1},{-1,1,1,-1,1,1,1,-1,1,1},{-1,1,1,1,-1,-1,1,-1,-1,1},{-1,1,1,1,1,1,1,-1,-1,-1},
 {1,-1,-1,-1,-1,1,1,-1,-1,-1},{1,-1,-1,-1,1,-1,1,-1,-1,1},{1,-1,-1,1,-1,1,1,-1,1,1},{1,-1,-1,1,1,-1,1,-1,1,-1},
 {1,-1,1,-1,-1,1,1,1,1,-1},{1,-1,1,-1,1,-1,1,1,1,1},{1,-1,1,1,-1,1,1,1,-1,1},{1,-1,1,1,1,-1,1,1,-1,-1},
 {1,1,-1,-1,-1,1,-1,1,-1,-1},{1,1,-1,-1,1,-1,-1,1,-1,1},{1,1,-1,1,-1,1,-1,1,1,1},{1,1,-1,1,1,-1,-1,1,1,-1},
 {1,1,1,-1,-1,1,-1,-1,1,-1},{1,1,1,-1,1,-1,-1,-1,1,1},{1,1,1,1,-1,1,-1,-1,-1,1},{1,1,1,1,1,-1,-1,-1,-1,-1}};

// 10-bit sign mask per codeword (bit j set iff CB[k][j] == +1), derived at
// compile time from CB to avoid transcription errors.
struct CBMasks { uint32_t m[32]; };
static constexpr CBMasks make_masks() {
    CBMasks r{};
    for (int k = 0; k < 32; ++k) {
        uint32_t mm = 0;
        for (int j = 0; j < DIM; ++j)
            if (CB[k][j] > 0.0f) mm |= (1u << j);
        r.m[k] = mm;
    }
    return r;
}
static constexpr CBMasks CBM = make_masks();

__global__ __launch_bounds__(PTS) void softdec_kernel(
    const float* __restrict__ sig, float* __restrict__ out)
{
    // Two points (20 floats, 80 B) per thread: 80 % 16 == 0, so both load and
    // store sides are pure dwordx4 at 16-B alignment. No LDS, no barriers.
    const size_t t = (size_t)blockIdx.x * PTS + threadIdx.x;

    // ---- load: 5x global_load_dwordx4 ----
    const float4* __restrict__ gp = (const float4*)sig + t * 5;
    float x[2 * DIM];
    #pragma unroll
    for (int q = 0; q < 5; ++q) {
        const float4 v = gp[q];
        x[4 * q + 0] = v.x;
        x[4 * q + 1] = v.y;
        x[4 * q + 2] = v.z;
        x[4 * q + 3] = v.w;
    }

    // ---- 32 signed sums + argmax for BOTH points, interleaved for ILP.
    // Per-point summation order and strict-'>' tie rule identical to the
    // passing kernels (bit-identical numerics / tie behavior). ----
    float    bestA = -1e30f, bestB = -1e30f;
    uint32_t bmA   = 0u,     bmB   = 0u;       // codeword 0 mask (all -1)
    #pragma unroll
    for (int k = 0; k < 32; ++k) {
        float sA = 0.0f, sB = 0.0f;
        #pragma unroll
        for (int j = 0; j < DIM; ++j) {
            if (CB[k][j] > 0.0f) { sA += x[j]; sB += x[DIM + j]; }
            else                 { sA -= x[j]; sB -= x[DIM + j]; }
        }
        if (sA > bestA) { bestA = sA; bmA = CBM.m[k]; }
        if (sB > bestB) { bestB = sB; bmB = CBM.m[k]; }
    }

    // ---- reconstruct +-1.0f from mask bits (+1=0x3F800000, -1=0xBF800000,
    // differ only in bit 31) and store 5x global_store_dwordx4 ----
    const uint32_t comb = bmA | (bmB << DIM);   // 20 bits, element e -> bit e
    float4* __restrict__ op = (float4*)out + t * 5;
    #pragma unroll
    for (int q = 0; q < 5; ++q) {
        float4 v;
        v.x = __uint_as_float(0xBF800000u ^ (((comb >> (4 * q + 0)) & 1u) << 31));
        v.y = __uint_as_float(0xBF800000u ^ (((comb >> (4 * q + 1)) & 1u) << 31));
        v.z = __uint_as_float(0xBF800000u ^ (((comb >> (4 * q + 2)) & 1u) << 31));
        v.w = __uint_as_float(0xBF800000u ^ (((comb >> (4 * q + 3)) & 1u) << 31));
        op[q] = v;
    }
}

extern "C" void kernel_launch(void* const* d_in, const int* in_sizes, int n_in,
                              void* d_out, int out_size, void* d_ws, size_t ws_size,
                              hipStream_t stream) {
    const float* sig = (const float*)d_in[0];
    float* out = (float*)d_out;
    const int total  = in_sizes[0];            // B*N*D = 41,943,040 floats
    const int pts    = total / DIM;            // 4,194,304 points
    const int blocks = pts / (PTS * PPT);      // 8,192 blocks (exact)
    softdec_kernel<<<blocks, PTS, 0, stream>>>(sig, out);
}

// Round 3
// 284.236 us; speedup vs baseline: 1.0541x; 1.0541x over previous
//
#include <hip/hip_runtime.h>
#include <stdint.h>

#define PTS    256                 // threads per block == points per block
#define DIM    10
#define FLOATS (PTS * DIM)         // 2560 floats per block chunk
#define VECS   (FLOATS / 4)        // 640 float4 per block chunk

// Codebook as compile-time constant. Fully unrolled uses constant-fold:
// dot loop -> add/sub chain, mask table -> inline cndmask constants.
static constexpr float CB[32][10] = {
 {-1,-1,-1,-1,-1,-1,-1,-1,-1,-1},{-1,-1,-1,-1,1,1,-1,-1,-1,1},{-1,-1,-1,1,-1,-1,-1,-1,1,1},{-1,-1,-1,1,1,1,-1,-1,1,-1},
 {-1,-1,1,-1,-1,-1,-1,1,1,-1},{-1,-1,1,-1,1,1,-1,1,1,1},{-1,-1,1,1,-1,-1,-1,1,-1,1},{-1,-1,1,1,1,1,-1,1,-1,-1},
 {-1,1,-1,-1,-1,-1,1,1,-1,-1},{-1,1,-1,-1,1,1,1,1,-1,1},{-1,1,-1,1,-1,-1,1,1,1,1},{-1,1,-1,1,1,1,1,1,1,-1},
 {-1,1,1,-1,-1,-1,1,-1,1,-1},{-1,1,1,-1,1,1,1,-1,1,1},{-1,1,1,1,-1,-1,1,-1,-1,1},{-1,1,1,1,1,1,1,-1,-1,-1},
 {1,-1,-1,-1,-1,1,1,-1,-1,-1},{1,-1,-1,-1,1,-1,1,-1,-1,1},{1,-1,-1,1,-1,1,1,-1,1,1},{1,-1,-1,1,1,-1,1,-1,1,-1},
 {1,-1,1,-1,-1,1,1,1,1,-1},{1,-1,1,-1,1,-1,1,1,1,1},{1,-1,1,1,-1,1,1,1,-1,1},{1,-1,1,1,1,-1,1,1,-1,-1},
 {1,1,-1,-1,-1,1,-1,1,-1,-1},{1,1,-1,-1,1,-1,-1,1,-1,1},{1,1,-1,1,-1,1,-1,1,1,1},{1,1,-1,1,1,-1,-1,1,1,-1},
 {1,1,1,-1,-1,1,-1,-1,1,-1},{1,1,1,-1,1,-1,-1,-1,1,1},{1,1,1,1,-1,1,-1,-1,-1,1},{1,1,1,1,1,-1,-1,-1,-1,-1}};

// 10-bit sign mask per codeword (bit j set iff CB[k][j] == +1), derived at
// compile time from CB to avoid transcription errors.
struct CBMasks { uint32_t m[32]; };
static constexpr CBMasks make_masks() {
    CBMasks r{};
    for (int k = 0; k < 32; ++k) {
        uint32_t mm = 0;
        for (int j = 0; j < DIM; ++j)
            if (CB[k][j] > 0.0f) mm |= (1u << j);
        r.m[k] = mm;
    }
    return r;
}
static constexpr CBMasks CBM = make_masks();

__global__ __launch_bounds__(PTS) void softdec_kernel(
    const float* __restrict__ sig, float* __restrict__ out)
{
    // LINEAR input staging (no scatter math) + 1-u32-per-point mask exchange.
    __shared__ float    sIn[FLOATS];     // 10 KiB, linear block chunk
    __shared__ uint32_t sMask[PTS];      // winning-codeword sign mask per point

    const int    tid  = threadIdx.x;
    const size_t base = (size_t)blockIdx.x * FLOATS;

    // ---- stage in: coalesced global_load_dwordx4 -> linear LDS ----
    const float4* __restrict__ gin  = (const float4*)(sig + base);
    float4*                    sIn4 = (float4*)sIn;
    #pragma unroll
    for (int it = 0; it < 3; ++it) {
        const int i = tid + it * PTS;    // 0..767, valid < 640
        if (i < VECS) sIn4[i] = gin[i];
    }
    __syncthreads();

    // ---- per-thread point from LDS (5x ds_read_b64, ~4-way alias: cheap) ----
    float x[DIM];
    #pragma unroll
    for (int j = 0; j < DIM; ++j) x[j] = sIn[tid * DIM + j];

    // ---- 32 signed sums + argmax. IDENTICAL summation order and strict-'>'
    // tie rule as the passing kernels (bit-identical numerics/ties). ----
    float    best = -1e30f;
    uint32_t bm   = 0u;                          // codeword 0 mask (all -1)
    #pragma unroll
    for (int k = 0; k < 32; ++k) {
        float s = 0.0f;
        #pragma unroll
        for (int j = 0; j < DIM; ++j)
            s = (CB[k][j] > 0.0f) ? (s + x[j]) : (s - x[j]);   // add/sub chain
        if (s > best) { best = s; bm = CBM.m[k]; }             // cmp + cndmask
    }

    sMask[tid] = bm;
    __syncthreads();

    // ---- stage out: compose coalesced float4 from mask bits.
    // +1.0f = 0x3F800000, -1.0f = 0xBF800000: differ only in bit 31. ----
    float4* __restrict__ gout = (float4*)(out + base);
    #pragma unroll
    for (int it = 0; it < 3; ++it) {
        const int i = tid + it * PTS;
        if (i < VECS) {
            float4 v;
            float* vv = (float*)&v;
            #pragma unroll
            for (int j = 0; j < 4; ++j) {
                const int gg = 4 * i + j;        // flat element in block chunk
                const int pp = gg / DIM;         // magic-mul div by 10
                const int cc = gg - pp * DIM;
                vv[j] = __uint_as_float(
                    0xBF800000u ^ (((sMask[pp] >> cc) & 1u) << 31));
            }
            gout[i] = v;                          // global_store_dwordx4
        }
    }
}

extern "C" void kernel_launch(void* const* d_in, const int* in_sizes, int n_in,
                              void* d_out, int out_size, void* d_ws, size_t ws_size,
                              hipStream_t stream) {
    const float* sig = (const float*)d_in[0];
    float* out = (float*)d_out;
    const int total  = in_sizes[0];        // B*N*D = 41,943,040 floats
    const int pts    = total / DIM;        // 4,194,304 points
    const int blocks = pts / PTS;          // 16,384 blocks (exact)
    softdec_kernel<<<blocks, PTS, 0, stream>>>(sig, out);
}